// Round 1
// baseline (2433.405 us; speedup 1.0000x reference)
//
#include <hip/hip_runtime.h>

#define NI 64      // instances
#define CH 64      // channels
#define EPSV 1e-5f
#define PADW 65    // padded LDS row width to break bank-conflict pattern

// ---------------- K1: per-instance sum & sum-of-squares + counts ----------------
// 1024 threads/block: 16 threads per point (4 channels each, float4), 64 points/iter.
__global__ __launch_bounds__(1024) void k_stats(const float* __restrict__ f,
                                                const int* __restrict__ seg,
                                                float* __restrict__ g_s,
                                                float* __restrict__ g_s2,
                                                unsigned* __restrict__ g_cnt,
                                                float* __restrict__ part, // [gridDim][8192] or unused
                                                int mode, int n) {
  __shared__ float ls[NI * PADW];
  __shared__ float ls2[NI * PADW];
  __shared__ unsigned lcnt[NI];
  const int t = threadIdx.x;
  for (int i = t; i < NI * PADW; i += 1024) { ls[i] = 0.f; ls2[i] = 0.f; }
  if (t < NI) lcnt[t] = 0u;
  __syncthreads();

  const int sub = t & 15;
  const int c0 = sub << 2;
  const int pib = t >> 4;                    // 0..63
  const int pstride = gridDim.x << 6;        // 64 points per block-iter
  for (int p = (blockIdx.x << 6) + pib; p < n; p += pstride) {
    const float4 v = *reinterpret_cast<const float4*>(f + (size_t)p * CH + c0);
    const int ins = seg[p];
    const int b = ins * PADW + c0;
    atomicAdd(&ls[b + 0], v.x);
    atomicAdd(&ls[b + 1], v.y);
    atomicAdd(&ls[b + 2], v.z);
    atomicAdd(&ls[b + 3], v.w);
    atomicAdd(&ls2[b + 0], v.x * v.x);
    atomicAdd(&ls2[b + 1], v.y * v.y);
    atomicAdd(&ls2[b + 2], v.z * v.z);
    atomicAdd(&ls2[b + 3], v.w * v.w);
    if (sub == 0) atomicAdd(&lcnt[ins], 1u);
  }
  __syncthreads();

  if (mode) {  // partial-buffer flush (no global float atomics)
    float* myp = part + (size_t)blockIdx.x * (2 * NI * CH);
    for (int i = t; i < NI * CH; i += 1024) {
      const int a = (i >> 6) * PADW + (i & 63);
      myp[i] = ls[a];
      myp[i + NI * CH] = ls2[a];
    }
  } else {
    for (int i = t; i < NI * CH; i += 1024) {
      const int a = (i >> 6) * PADW + (i & 63);
      atomicAdd(&g_s[i], ls[a]);
      atomicAdd(&g_s2[i], ls2[a]);
    }
  }
  if (t < NI) atomicAdd(&g_cnt[t], lcnt[t]);
}

// ---------------- generic partial reducer: dst[e] = sum_b part[b*len+e] ----------------
__global__ __launch_bounds__(256) void k_reduce(const float* __restrict__ part,
                                                float* __restrict__ dst,
                                                int nblk, int len) {
  const int e = blockIdx.x * 256 + threadIdx.x;
  if (e >= len) return;
  float acc = 0.f;
  for (int b = 0; b < nblk; ++b) acc += part[(size_t)b * len + e];
  dst[e] = acc;
}

// ---------------- K2: inv = rsqrt(var+eps), mi = mu*inv ----------------
__global__ __launch_bounds__(256) void k_musig(const float* __restrict__ g_s,
                                               const float* __restrict__ g_s2,
                                               const unsigned* __restrict__ g_cnt,
                                               float* __restrict__ g_inv,
                                               float* __restrict__ g_mi) {
  const int i = blockIdx.x * 256 + threadIdx.x;  // grid = 16 -> 4096 threads
  const float c = fmaxf((float)g_cnt[i >> 6], 1.f);
  const float mu = g_s[i] / c;
  const float var = fmaxf(g_s2[i] / c - mu * mu, 0.f);
  const float inv = rsqrtf(var + EPSV);
  g_inv[i] = inv;
  g_mi[i] = mu * inv;
}

// ---------------- K3: segment-sum of relu(fma(f, inv, -mi)) ----------------
__global__ __launch_bounds__(1024) void k_rsum(const float* __restrict__ f,
                                               const int* __restrict__ seg,
                                               const float* __restrict__ g_inv,
                                               const float* __restrict__ g_mi,
                                               float* __restrict__ g_rsum,
                                               float* __restrict__ part, // [gridDim][4096]
                                               int mode, int n) {
  __shared__ float tinv[NI * CH];
  __shared__ float tmi[NI * CH];
  __shared__ float lr[NI * PADW];
  const int t = threadIdx.x;
  for (int i = t; i < NI * CH; i += 1024) { tinv[i] = g_inv[i]; tmi[i] = g_mi[i]; }
  for (int i = t; i < NI * PADW; i += 1024) lr[i] = 0.f;
  __syncthreads();

  const int sub = t & 15;
  const int c0 = sub << 2;
  const int pib = t >> 4;
  const int pstride = gridDim.x << 6;
  for (int p = (blockIdx.x << 6) + pib; p < n; p += pstride) {
    const float4 v = *reinterpret_cast<const float4*>(f + (size_t)p * CH + c0);
    const int ins = seg[p];
    const int tb = (ins << 6) + c0;
    const float4 iv = *reinterpret_cast<const float4*>(tinv + tb);
    const float4 mi = *reinterpret_cast<const float4*>(tmi + tb);
    const float x0 = fmaxf(fmaf(v.x, iv.x, -mi.x), 0.f);
    const float x1 = fmaxf(fmaf(v.y, iv.y, -mi.y), 0.f);
    const float x2 = fmaxf(fmaf(v.z, iv.z, -mi.z), 0.f);
    const float x3 = fmaxf(fmaf(v.w, iv.w, -mi.w), 0.f);
    const int b = ins * PADW + c0;
    atomicAdd(&lr[b + 0], x0);
    atomicAdd(&lr[b + 1], x1);
    atomicAdd(&lr[b + 2], x2);
    atomicAdd(&lr[b + 3], x3);
  }
  __syncthreads();

  if (mode) {
    float* myp = part + (size_t)blockIdx.x * (NI * CH);
    for (int i = t; i < NI * CH; i += 1024)
      myp[i] = lr[(i >> 6) * PADW + (i & 63)];
  } else {
    for (int i = t; i < NI * CH; i += 1024)
      atomicAdd(&g_rsum[i], lr[(i >> 6) * PADW + (i & 63)]);
  }
}

// ---------------- K4: m = rsum/cnt -> conv3 -> sigmoid -> A = inv*w, B = mi*w ----------------
__global__ __launch_bounds__(256) void k_eca(const float* __restrict__ g_rsum,
                                             const unsigned* __restrict__ g_cnt,
                                             const float* __restrict__ ew,
                                             const float* __restrict__ g_inv,
                                             const float* __restrict__ g_mi,
                                             float* __restrict__ g_A,
                                             float* __restrict__ g_B) {
  __shared__ float m[NI * CH];
  const int t = threadIdx.x;
  for (int i = t; i < NI * CH; i += 256)
    m[i] = g_rsum[i] / fmaxf((float)g_cnt[i >> 6], 1.f);
  __syncthreads();
  const float e0 = ew[0], e1 = ew[1], e2 = ew[2];
  for (int i = t; i < NI * CH; i += 256) {
    const int c = i & 63;
    const float a = c ? m[i - 1] : 0.f;
    const float b = m[i];
    const float d = (c < 63) ? m[i + 1] : 0.f;
    const float conv = e0 * a + e1 * b + e2 * d;
    const float w = 1.f / (1.f + expf(-conv));
    g_A[i] = g_inv[i] * w;
    g_B[i] = g_mi[i] * w;
  }
}

// ---------------- K5: out = relu(fma(f, A, -B)) ----------------
__global__ __launch_bounds__(256) void k_out(const float* __restrict__ f,
                                             const int* __restrict__ seg,
                                             const float* __restrict__ g_A,
                                             const float* __restrict__ g_B,
                                             float* __restrict__ out,
                                             int n) {
  __shared__ float tA[NI * CH];
  __shared__ float tB[NI * CH];
  const int t = threadIdx.x;
  for (int i = t; i < NI * CH; i += 256) { tA[i] = g_A[i]; tB[i] = g_B[i]; }
  __syncthreads();

  const int sub = t & 15;
  const int c0 = sub << 2;
  const int pib = t >> 4;                 // 0..15, 16 points per block-iter
  const int pstride = gridDim.x << 4;
  for (int p = (blockIdx.x << 4) + pib; p < n; p += pstride) {
    const float4 v = *reinterpret_cast<const float4*>(f + (size_t)p * CH + c0);
    const int ins = seg[p];
    const int tb = (ins << 6) + c0;
    const float4 a = *reinterpret_cast<const float4*>(tA + tb);
    const float4 b = *reinterpret_cast<const float4*>(tB + tb);
    float4 o;
    o.x = fmaxf(fmaf(v.x, a.x, -b.x), 0.f);
    o.y = fmaxf(fmaf(v.y, a.y, -b.y), 0.f);
    o.z = fmaxf(fmaf(v.z, a.z, -b.z), 0.f);
    o.w = fmaxf(fmaf(v.w, a.w, -b.w), 0.f);
    *reinterpret_cast<float4*>(out + (size_t)p * CH + c0) = o;
  }
}

// ---------------- launch ----------------
extern "C" void kernel_launch(void* const* d_in, const int* in_sizes, int n_in,
                              void* d_out, int out_size, void* d_ws, size_t ws_size,
                              hipStream_t stream) {
  const float* f   = (const float*)d_in[0];
  const int*   seg = (const int*)d_in[1];
  const float* ew  = (const float*)d_in[2];
  float* out = (float*)d_out;
  const int n = in_sizes[1];  // number of points

  // workspace layout (float offsets)
  float* ws     = (float*)d_ws;
  float* g_s    = ws;                 // 4096
  float* g_s2   = ws + 4096;          // 4096  (contiguous with g_s for combined reduce)
  float* g_rsum = ws + 8192;          // 4096
  unsigned* g_cnt = (unsigned*)(ws + 12288);  // 64 u32
  float* g_inv  = ws + 12352;         // 4096
  float* g_mi   = ws + 16448;         // 4096
  float* g_A    = ws + 20544;         // 4096
  float* g_B    = ws + 24640;         // 4096
  float* part1  = ws + 28736;         // NBLK * 8192
  const int NBLK = 512;               // 2 blocks/CU x 256 CU, 1024 threads each
  float* part3  = part1 + (size_t)NBLK * 8192;  // NBLK * 4096
  const size_t need_bytes = (28736 + (size_t)NBLK * 8192 + (size_t)NBLK * 4096) * 4;
  const int mode = (ws_size >= need_bytes) ? 1 : 0;  // 1: partial-buffer flush, 0: atomic flush

  // zero accumulators (g_s, g_s2, g_rsum, g_cnt) = first 12352 floats
  hipMemsetAsync(d_ws, 0, (12288 + 64) * sizeof(float), stream);

  k_stats<<<NBLK, 1024, 0, stream>>>(f, seg, g_s, g_s2, g_cnt, part1, mode, n);
  if (mode)
    k_reduce<<<32, 256, 0, stream>>>(part1, g_s /* covers g_s+g_s2 */, NBLK, 8192);
  k_musig<<<16, 256, 0, stream>>>(g_s, g_s2, g_cnt, g_inv, g_mi);
  k_rsum<<<NBLK, 1024, 0, stream>>>(f, seg, g_inv, g_mi, g_rsum, part3, mode, n);
  if (mode)
    k_reduce<<<16, 256, 0, stream>>>(part3, g_rsum, NBLK, 4096);
  k_eca<<<1, 256, 0, stream>>>(g_rsum, g_cnt, ew, g_inv, g_mi, g_A, g_B);
  k_out<<<2048, 256, 0, stream>>>(f, seg, g_A, g_B, out, n);
}

// Round 2
// 446.970 us; speedup vs baseline: 5.4442x; 5.4442x over previous
//
#include <hip/hip_runtime.h>

#define NI 64      // instances
#define CH 64      // channels
#define EPSV 1e-5f
#define KB 32      // blocks per instance in binned passes
#define PADT 66    // padded LDS table row for k_out
#define PADW 65    // fallback-path padding

// ================= binned path =================

// ---- K0: per-instance counts ----
__global__ __launch_bounds__(256) void k_hist(const int* __restrict__ seg,
                                              unsigned* __restrict__ hist, int n) {
  __shared__ unsigned h[NI];
  const int t = threadIdx.x;
  if (t < NI) h[t] = 0u;
  __syncthreads();
  const int stride = gridDim.x * 256;
  const int n4 = n >> 2;
  for (int i = blockIdx.x * 256 + t; i < n4; i += stride) {
    const int4 s = reinterpret_cast<const int4*>(seg)[i];
    atomicAdd(&h[s.x], 1u); atomicAdd(&h[s.y], 1u);
    atomicAdd(&h[s.z], 1u); atomicAdd(&h[s.w], 1u);
  }
  if (blockIdx.x == 0)
    for (int i = (n4 << 2) + t; i < n; i += 256) atomicAdd(&h[seg[i]], 1u);
  __syncthreads();
  if (t < NI) atomicAdd(&hist[t], h[t]);
}

// ---- K1: exclusive scan (64 entries) ----
__global__ void k_scan(const unsigned* __restrict__ hist,
                       unsigned* __restrict__ off, unsigned* __restrict__ cur) {
  if (threadIdx.x == 0) {
    unsigned acc = 0;
    for (int i = 0; i < NI; ++i) { off[i] = acc; cur[i] = acc; acc += hist[i]; }
    off[NI] = acc;
  }
}

// ---- K2: scatter point indices into instance bins ----
__global__ __launch_bounds__(256) void k_scatter(const int* __restrict__ seg,
                                                 unsigned* __restrict__ g_cur,
                                                 unsigned* __restrict__ perm, int n) {
  __shared__ int stash[8192];
  __shared__ unsigned h[NI];
  __shared__ unsigned base[NI];
  const int t = threadIdx.x;
  const int start = blockIdx.x * 8192;
  const int len = min(8192, n - start);
  if (t < NI) h[t] = 0u;
  __syncthreads();
  for (int i = t; i < len; i += 256) {
    const int s = seg[start + i];
    stash[i] = s;
    atomicAdd(&h[s], 1u);
  }
  __syncthreads();
  if (t < NI) { base[t] = atomicAdd(&g_cur[t], h[t]); h[t] = 0u; }
  __syncthreads();
  for (int i = t; i < len; i += 256) {
    const int s = stash[i];
    const unsigned r = atomicAdd(&h[s], 1u);
    perm[base[s] + r] = (unsigned)(start + i);
  }
}

// ---- K3: per-instance sum & sumsq, register accumulation ----
__global__ __launch_bounds__(256) void k_stats_b(const float* __restrict__ f,
                                                 const unsigned* __restrict__ perm,
                                                 const unsigned* __restrict__ off,
                                                 float* __restrict__ g_s,
                                                 float* __restrict__ g_s2) {
  __shared__ float red[4][128];
  const int ins = blockIdx.x >> 5;
  const int k = blockIdx.x & (KB - 1);
  const unsigned lo = off[ins], len = off[ins + 1] - lo;
  const unsigned a = lo + ((len * (unsigned)k) >> 5);
  const unsigned b = lo + ((len * (unsigned)(k + 1)) >> 5);
  const int t = threadIdx.x;
  const int lane = t & 63;
  const int wv = t >> 6;           // 4 waves
  const int psub = lane >> 4;      // 4 points per wave-iter
  const int c0 = (lane & 15) << 2; // 4 channels per lane
  float4 s = {0.f, 0.f, 0.f, 0.f}, s2 = {0.f, 0.f, 0.f, 0.f};
  for (unsigned i = a + (unsigned)(wv * 4 + psub); i < b; i += 16) {
    const unsigned p = perm[i];
    const float4 v = *reinterpret_cast<const float4*>(f + (size_t)p * CH + c0);
    s.x += v.x; s.y += v.y; s.z += v.z; s.w += v.w;
    s2.x = fmaf(v.x, v.x, s2.x); s2.y = fmaf(v.y, v.y, s2.y);
    s2.z = fmaf(v.z, v.z, s2.z); s2.w = fmaf(v.w, v.w, s2.w);
  }
  // reduce across psub (lanes xor 16, 32)
  s.x += __shfl_xor(s.x, 16); s.y += __shfl_xor(s.y, 16);
  s.z += __shfl_xor(s.z, 16); s.w += __shfl_xor(s.w, 16);
  s.x += __shfl_xor(s.x, 32); s.y += __shfl_xor(s.y, 32);
  s.z += __shfl_xor(s.z, 32); s.w += __shfl_xor(s.w, 32);
  s2.x += __shfl_xor(s2.x, 16); s2.y += __shfl_xor(s2.y, 16);
  s2.z += __shfl_xor(s2.z, 16); s2.w += __shfl_xor(s2.w, 16);
  s2.x += __shfl_xor(s2.x, 32); s2.y += __shfl_xor(s2.y, 32);
  s2.z += __shfl_xor(s2.z, 32); s2.w += __shfl_xor(s2.w, 32);
  if (psub == 0) {
    *reinterpret_cast<float4*>(&red[wv][c0]) = s;
    *reinterpret_cast<float4*>(&red[wv][64 + c0]) = s2;
  }
  __syncthreads();
  if (t < 128) {
    const float v = red[0][t] + red[1][t] + red[2][t] + red[3][t];
    float* dst = (t < 64) ? (g_s + ins * CH + t) : (g_s2 + ins * CH + (t - 64));
    atomicAdd(dst, v);
  }
}

// ---- K4: inv = rsqrt(var+eps), mi = mu*inv ----
__global__ __launch_bounds__(256) void k_musig(const float* __restrict__ g_s,
                                               const float* __restrict__ g_s2,
                                               const unsigned* __restrict__ cnt,
                                               float* __restrict__ g_inv,
                                               float* __restrict__ g_mi) {
  const int i = blockIdx.x * 256 + threadIdx.x;  // grid 16 -> 4096
  const float c = fmaxf((float)cnt[i >> 6], 1.f);
  const float mu = g_s[i] / c;
  const float var = fmaxf(g_s2[i] / c - mu * mu, 0.f);
  const float inv = rsqrtf(var + EPSV);
  g_inv[i] = inv;
  g_mi[i] = mu * inv;
}

// ---- K5: segment-sum of relu(fma(f,inv,-mi)), binned ----
__global__ __launch_bounds__(256) void k_rsum_b(const float* __restrict__ f,
                                                const unsigned* __restrict__ perm,
                                                const unsigned* __restrict__ off,
                                                const float* __restrict__ g_inv,
                                                const float* __restrict__ g_mi,
                                                float* __restrict__ g_rsum) {
  __shared__ float red[4][64];
  const int ins = blockIdx.x >> 5;
  const int k = blockIdx.x & (KB - 1);
  const unsigned lo = off[ins], len = off[ins + 1] - lo;
  const unsigned a = lo + ((len * (unsigned)k) >> 5);
  const unsigned b = lo + ((len * (unsigned)(k + 1)) >> 5);
  const int t = threadIdx.x;
  const int lane = t & 63;
  const int wv = t >> 6;
  const int psub = lane >> 4;
  const int c0 = (lane & 15) << 2;
  const float4 iv = *reinterpret_cast<const float4*>(g_inv + ins * CH + c0);
  const float4 mi = *reinterpret_cast<const float4*>(g_mi + ins * CH + c0);
  float4 r = {0.f, 0.f, 0.f, 0.f};
  for (unsigned i = a + (unsigned)(wv * 4 + psub); i < b; i += 16) {
    const unsigned p = perm[i];
    const float4 v = *reinterpret_cast<const float4*>(f + (size_t)p * CH + c0);
    r.x += fmaxf(fmaf(v.x, iv.x, -mi.x), 0.f);
    r.y += fmaxf(fmaf(v.y, iv.y, -mi.y), 0.f);
    r.z += fmaxf(fmaf(v.z, iv.z, -mi.z), 0.f);
    r.w += fmaxf(fmaf(v.w, iv.w, -mi.w), 0.f);
  }
  r.x += __shfl_xor(r.x, 16); r.y += __shfl_xor(r.y, 16);
  r.z += __shfl_xor(r.z, 16); r.w += __shfl_xor(r.w, 16);
  r.x += __shfl_xor(r.x, 32); r.y += __shfl_xor(r.y, 32);
  r.z += __shfl_xor(r.z, 32); r.w += __shfl_xor(r.w, 32);
  if (psub == 0) *reinterpret_cast<float4*>(&red[wv][c0]) = r;
  __syncthreads();
  if (t < 64)
    atomicAdd(&g_rsum[ins * CH + t], red[0][t] + red[1][t] + red[2][t] + red[3][t]);
}

// ---- K6: m = rsum/cnt -> conv3 -> sigmoid -> A = inv*w, B = mi*w ----
__global__ __launch_bounds__(256) void k_eca(const float* __restrict__ g_rsum,
                                             const unsigned* __restrict__ cnt,
                                             const float* __restrict__ ew,
                                             const float* __restrict__ g_inv,
                                             const float* __restrict__ g_mi,
                                             float* __restrict__ g_A,
                                             float* __restrict__ g_B) {
  __shared__ float m[NI * CH];
  const int t = threadIdx.x;
  for (int i = t; i < NI * CH; i += 256)
    m[i] = g_rsum[i] / fmaxf((float)cnt[i >> 6], 1.f);
  __syncthreads();
  const float e0 = ew[0], e1 = ew[1], e2 = ew[2];
  for (int i = t; i < NI * CH; i += 256) {
    const int c = i & 63;
    const float a = c ? m[i - 1] : 0.f;
    const float b = m[i];
    const float d = (c < 63) ? m[i + 1] : 0.f;
    const float conv = e0 * a + e1 * b + e2 * d;
    const float w = 1.f / (1.f + expf(-conv));
    g_A[i] = g_inv[i] * w;
    g_B[i] = g_mi[i] * w;
  }
}

// ---- K7: out = relu(fma(f, A, -B)), streaming ----
__global__ __launch_bounds__(256) void k_out(const float* __restrict__ f,
                                             const int* __restrict__ seg,
                                             const float* __restrict__ g_A,
                                             const float* __restrict__ g_B,
                                             float* __restrict__ out,
                                             int n) {
  __shared__ float tA[NI * PADT];
  __shared__ float tB[NI * PADT];
  const int t = threadIdx.x;
  for (int i = t; i < NI * CH; i += 256) {
    const int a = (i >> 6) * PADT + (i & 63);
    tA[a] = g_A[i];
    tB[a] = g_B[i];
  }
  __syncthreads();
  const int sub = t & 15;
  const int c0 = sub << 2;
  const int pib = t >> 4;
  const int pstride = gridDim.x << 4;
  for (int p = (blockIdx.x << 4) + pib; p < n; p += pstride) {
    const float4 v = *reinterpret_cast<const float4*>(f + (size_t)p * CH + c0);
    const int tb = seg[p] * PADT + c0;
    const float4 a = *reinterpret_cast<const float4*>(tA + tb);
    const float4 b = *reinterpret_cast<const float4*>(tB + tb);
    float4 o;
    o.x = fmaxf(fmaf(v.x, a.x, -b.x), 0.f);
    o.y = fmaxf(fmaf(v.y, a.y, -b.y), 0.f);
    o.z = fmaxf(fmaf(v.z, a.z, -b.z), 0.f);
    o.w = fmaxf(fmaf(v.w, a.w, -b.w), 0.f);
    *reinterpret_cast<float4*>(out + (size_t)p * CH + c0) = o;
  }
}

// ================= fallback path (ws too small for perm) =================
__global__ __launch_bounds__(1024) void k_stats_f(const float* __restrict__ f,
                                                  const int* __restrict__ seg,
                                                  float* __restrict__ g_s,
                                                  float* __restrict__ g_s2,
                                                  unsigned* __restrict__ g_cnt, int n) {
  __shared__ float ls[NI * PADW];
  __shared__ float ls2[NI * PADW];
  __shared__ unsigned lcnt[NI];
  const int t = threadIdx.x;
  for (int i = t; i < NI * PADW; i += 1024) { ls[i] = 0.f; ls2[i] = 0.f; }
  if (t < NI) lcnt[t] = 0u;
  __syncthreads();
  const int sub = t & 15, c0 = sub << 2, pib = t >> 4;
  const int pstride = gridDim.x << 6;
  for (int p = (blockIdx.x << 6) + pib; p < n; p += pstride) {
    const float4 v = *reinterpret_cast<const float4*>(f + (size_t)p * CH + c0);
    const int b = seg[p] * PADW + c0;
    atomicAdd(&ls[b + 0], v.x); atomicAdd(&ls[b + 1], v.y);
    atomicAdd(&ls[b + 2], v.z); atomicAdd(&ls[b + 3], v.w);
    atomicAdd(&ls2[b + 0], v.x * v.x); atomicAdd(&ls2[b + 1], v.y * v.y);
    atomicAdd(&ls2[b + 2], v.z * v.z); atomicAdd(&ls2[b + 3], v.w * v.w);
    if (sub == 0) atomicAdd(&lcnt[seg[p]], 1u);
  }
  __syncthreads();
  for (int i = t; i < NI * CH; i += 1024) {
    const int a = (i >> 6) * PADW + (i & 63);
    atomicAdd(&g_s[i], ls[a]);
    atomicAdd(&g_s2[i], ls2[a]);
  }
  if (t < NI) atomicAdd(&g_cnt[t], lcnt[t]);
}

__global__ __launch_bounds__(1024) void k_rsum_f(const float* __restrict__ f,
                                                 const int* __restrict__ seg,
                                                 const float* __restrict__ g_inv,
                                                 const float* __restrict__ g_mi,
                                                 float* __restrict__ g_rsum, int n) {
  __shared__ float tinv[NI * CH];
  __shared__ float tmi[NI * CH];
  __shared__ float lr[NI * PADW];
  const int t = threadIdx.x;
  for (int i = t; i < NI * CH; i += 1024) { tinv[i] = g_inv[i]; tmi[i] = g_mi[i]; }
  for (int i = t; i < NI * PADW; i += 1024) lr[i] = 0.f;
  __syncthreads();
  const int sub = t & 15, c0 = sub << 2, pib = t >> 4;
  const int pstride = gridDim.x << 6;
  for (int p = (blockIdx.x << 6) + pib; p < n; p += pstride) {
    const float4 v = *reinterpret_cast<const float4*>(f + (size_t)p * CH + c0);
    const int ins = seg[p];
    const int tb = (ins << 6) + c0;
    const float4 iv = *reinterpret_cast<const float4*>(tinv + tb);
    const float4 mi = *reinterpret_cast<const float4*>(tmi + tb);
    const int b = ins * PADW + c0;
    atomicAdd(&lr[b + 0], fmaxf(fmaf(v.x, iv.x, -mi.x), 0.f));
    atomicAdd(&lr[b + 1], fmaxf(fmaf(v.y, iv.y, -mi.y), 0.f));
    atomicAdd(&lr[b + 2], fmaxf(fmaf(v.z, iv.z, -mi.z), 0.f));
    atomicAdd(&lr[b + 3], fmaxf(fmaf(v.w, iv.w, -mi.w), 0.f));
  }
  __syncthreads();
  for (int i = t; i < NI * CH; i += 1024)
    atomicAdd(&g_rsum[i], lr[(i >> 6) * PADW + (i & 63)]);
}

// ================= launch =================
extern "C" void kernel_launch(void* const* d_in, const int* in_sizes, int n_in,
                              void* d_out, int out_size, void* d_ws, size_t ws_size,
                              hipStream_t stream) {
  const float* f   = (const float*)d_in[0];
  const int*   seg = (const int*)d_in[1];
  const float* ew  = (const float*)d_in[2];
  float* out = (float*)d_out;
  const int n = in_sizes[1];

  // ws layout (float offsets)
  float* ws      = (float*)d_ws;
  float* g_s     = ws;                       // 4096
  float* g_s2    = ws + 4096;                // 4096
  float* g_rsum  = ws + 8192;                // 4096
  unsigned* hist = (unsigned*)(ws + 12288);  // 64 (also counts)
  unsigned* off  = hist + 64;                // 65
  unsigned* cur  = off + 65;                 // 64   (193 used, 256 reserved)
  float* g_inv   = ws + 12544;               // 4096
  float* g_mi    = ws + 16640;               // 4096
  float* g_A     = ws + 20736;               // 4096
  float* g_B     = ws + 24832;               // 4096
  unsigned* perm = (unsigned*)(ws + 28928);  // n
  const size_t need = (size_t)(28928 + n) * 4;

  // zero accumulators: g_s, g_s2, g_rsum, hist
  hipMemsetAsync(d_ws, 0, (12288 + 64) * sizeof(float), stream);

  if (ws_size >= need) {
    k_hist<<<256, 256, 0, stream>>>(seg, hist, n);
    k_scan<<<1, 64, 0, stream>>>(hist, off, cur);
    k_scatter<<<(n + 8191) / 8192, 256, 0, stream>>>(seg, cur, perm, n);
    k_stats_b<<<NI * KB, 256, 0, stream>>>(f, perm, off, g_s, g_s2);
    k_musig<<<16, 256, 0, stream>>>(g_s, g_s2, hist, g_inv, g_mi);
    k_rsum_b<<<NI * KB, 256, 0, stream>>>(f, perm, off, g_inv, g_mi, g_rsum);
  } else {
    k_stats_f<<<512, 1024, 0, stream>>>(f, seg, g_s, g_s2, hist, n);
    k_musig<<<16, 256, 0, stream>>>(g_s, g_s2, hist, g_inv, g_mi);
    k_rsum_f<<<512, 1024, 0, stream>>>(f, seg, g_inv, g_mi, g_rsum, n);
  }
  k_eca<<<1, 256, 0, stream>>>(g_rsum, hist, ew, g_inv, g_mi, g_A, g_B);
  k_out<<<2048, 256, 0, stream>>>(f, seg, g_A, g_B, out, n);
}